// Round 2
// baseline (443.713 us; speedup 1.0000x reference)
//
#include <hip/hip_runtime.h>

#define NB 4
#define NC 2
#define ND 160
#define NH 160
#define NW 160
#define NG 8
#define NG3 (NG * NG * NG)   // 512

// mirror reflect t into [0, nm1], period 2*nm1 (scipy mode='mirror' /
// grid_sample reflection + align_corners=True)
__device__ __forceinline__ float reflect_mirror(float t, float nm1) {
    t = fabsf(t);
    if (t > nm1) {
        float p = 2.0f * nm1;
        t = t - p * floorf(t / p);   // fold into [0, p)
        if (t > nm1) t = p - t;
    }
    return t;
}

__global__ __launch_bounds__(256) void elastic_deform_kernel(
    const float* __restrict__ x,      // [B,C,D,H,W]
    const float* __restrict__ flow,   // [B,3,G,G,G]
    float* __restrict__ out)          // [B,C,D,H,W]
{
    const int HW  = NH * NW;
    const int DHW = ND * HW;

    // XCD-aware swizzle: HW dispatches blocks round-robin across 8 XCDs
    // (block i -> XCD i%8). Remap so each XCD owns a CONTIGUOUS 1/8 of the
    // volume -> y-row / z-plane reuse lands in that XCD's private L2.
    // grid (64000) is divisible by 8, DHW*NB divisible by 256: exact cover.
    int nblk  = gridDim.x;
    int chunk = nblk >> 3;
    int bid   = blockIdx.x;
    int eff   = (bid & 7) * chunk + (bid >> 3);
    int idx   = eff * 256 + (int)threadIdx.x;

    int w = idx % NW;
    int t = idx / NW;
    int h = t % NH;
    t /= NH;
    int d = t % ND;
    int b = t / ND;   // block-uniform: DHW divisible by 256

    // ---- stage this batch's coarse flow into LDS (6 KB) ----
    __shared__ float sflow[3 * NG3];
    {
        const float* fb = flow + b * 3 * NG3;
        for (int i = threadIdx.x; i < 3 * NG3; i += 256)
            sflow[i] = fb[i];
    }
    __syncthreads();

    // ---- upsample coarse flow at (d,h,w): trilinear, coords = i*(g-1)/(n-1)
    const float s = 7.0f / 159.0f;
    float cz = d * s, cy = h * s, cx = w * s;
    int iz0 = (int)cz, iy0 = (int)cy, ix0 = (int)cx;
    iz0 = min(iz0, NG - 1); iy0 = min(iy0, NG - 1); ix0 = min(ix0, NG - 1);
    float fz = cz - iz0, fy = cy - iy0, fx = cx - ix0;
    int iz1 = min(iz0 + 1, NG - 1);
    int iy1 = min(iy0 + 1, NG - 1);
    int ix1 = min(ix0 + 1, NG - 1);

    int o00 = (iz0 * NG + iy0) * NG;
    int o01 = (iz0 * NG + iy1) * NG;
    int o10 = (iz1 * NG + iy0) * NG;
    int o11 = (iz1 * NG + iy1) * NG;

    float up[3];
#pragma unroll
    for (int ch = 0; ch < 3; ++ch) {
        const float* f = sflow + ch * NG3;
        float c000 = f[o00 + ix0], c001 = f[o00 + ix1];
        float c010 = f[o01 + ix0], c011 = f[o01 + ix1];
        float c100 = f[o10 + ix0], c101 = f[o10 + ix1];
        float c110 = f[o11 + ix0], c111 = f[o11 + ix1];
        float a00 = c000 + (c001 - c000) * fx;
        float a01 = c010 + (c011 - c010) * fx;
        float a10 = c100 + (c101 - c100) * fx;
        float a11 = c110 + (c111 - c110) * fx;
        float a0 = a00 + (a01 - a00) * fy;
        float a1 = a10 + (a11 - a10) * fy;
        up[ch] = a0 + (a1 - a0) * fz;
    }

    // ---- sample coordinates (unnormalize collapses to voxel + disp*79.5)
    float sx = (float)w + up[0] * 79.5f;
    float sy = (float)h + up[1] * 79.5f;
    float sz = (float)d + up[2] * 79.5f;

    sx = reflect_mirror(sx, (float)(NW - 1));
    sy = reflect_mirror(sy, (float)(NH - 1));
    sz = reflect_mirror(sz, (float)(ND - 1));

    int x0 = (int)sx, y0 = (int)sy, z0 = (int)sz;
    x0 = min(x0, NW - 1); y0 = min(y0, NH - 1); z0 = min(z0, ND - 1);
    float gx = sx - x0, gy = sy - y0, gz = sz - z0;
    int x1 = min(x0 + 1, NW - 1);
    int y1 = min(y0 + 1, NH - 1);
    int z1 = min(z0 + 1, ND - 1);

    // 8 corner offsets within one [D,H,W] volume (shared across channels)
    int p000 = (z0 * NH + y0) * NW + x0;
    int p001 = (z0 * NH + y0) * NW + x1;
    int p010 = (z0 * NH + y1) * NW + x0;
    int p011 = (z0 * NH + y1) * NW + x1;
    int p100 = (z1 * NH + y0) * NW + x0;
    int p101 = (z1 * NH + y0) * NW + x1;
    int p110 = (z1 * NH + y1) * NW + x0;
    int p111 = (z1 * NH + y1) * NW + x1;

    float wx0 = 1.0f - gx, wy0 = 1.0f - gy, wz0 = 1.0f - gz;
    float w000 = wz0 * wy0 * wx0;
    float w001 = wz0 * wy0 * gx;
    float w010 = wz0 * gy  * wx0;
    float w011 = wz0 * gy  * gx;
    float w100 = gz  * wy0 * wx0;
    float w101 = gz  * wy0 * gx;
    float w110 = gz  * gy  * wx0;
    float w111 = gz  * gy  * gx;

    int opos = (d * NH + h) * NW + w;
#pragma unroll
    for (int c = 0; c < NC; ++c) {
        const float* xv = x + ((size_t)(b * NC + c)) * DHW;
        float v = xv[p000] * w000 + xv[p001] * w001
                + xv[p010] * w010 + xv[p011] * w011
                + xv[p100] * w100 + xv[p101] * w101
                + xv[p110] * w110 + xv[p111] * w111;
        // write-once output: nontemporal, don't pollute L2 gather working set
        __builtin_nontemporal_store(v, &out[((size_t)(b * NC + c)) * DHW + opos]);
    }
}

extern "C" void kernel_launch(void* const* d_in, const int* in_sizes, int n_in,
                              void* d_out, int out_size, void* d_ws, size_t ws_size,
                              hipStream_t stream) {
    const float* x    = (const float*)d_in[0];
    const float* flow = (const float*)d_in[1];
    float* out = (float*)d_out;
    int total = NB * ND * NH * NW;   // one thread per (b,d,h,w), both channels
    int block = 256;
    int grid = (total + block - 1) / block;
    elastic_deform_kernel<<<grid, block, 0, stream>>>(x, flow, out);
}

// Round 4
// 424.947 us; speedup vs baseline: 1.0442x; 1.0442x over previous
//
#include <hip/hip_runtime.h>

#define NB 4
#define NC 2
#define ND 160
#define NH 160
#define NW 160
#define NG 8
#define NG3 (NG * NG * NG)       // 512
#define HWSZ (NH * NW)
#define DHW (ND * HWSZ)
#define QPR (NW / 4)             // 40 quads per row
#define NQ (NB * DHW / 4)        // total quads = 4,096,000

typedef float v4f __attribute__((ext_vector_type(4)));   // native vector: OK for nontemporal builtin

// mirror reflect t into [0, nm1], period 2*nm1
__device__ __forceinline__ float reflect_mirror(float t, float nm1) {
    t = fabsf(t);
    if (t > nm1) {
        float p = 2.0f * nm1;
        t = t - p * floorf(t / p);
        if (t > nm1) t = p - t;
    }
    return t;
}

// linear interp of two ADJACENT floats (provably adjacent -> dwordx2)
__device__ __forceinline__ float lerp2(const float* __restrict__ p, float g) {
    float a = p[0], b = p[1];
    return a + (b - a) * g;
}

__global__ __launch_bounds__(256) void elastic_deform_kernel(
    const float* __restrict__ x,      // [B,C,D,H,W]
    const float* __restrict__ flow,   // [B,3,G,G,G]
    float* __restrict__ out)          // [B,C,D,H,W]
{
    // XCD chunk swizzle (kept from R2: fixed 3x HBM over-fetch)
    int nblk  = gridDim.x;
    int chunk = nblk >> 3;
    int bid   = blockIdx.x;
    int eff   = (bid & 7) * chunk + (bid >> 3);
    int q     = eff * 256 + (int)threadIdx.x;   // quad index

    int qw = q % QPR;
    int t  = q / QPR;
    int h  = t % NH;
    t /= NH;
    int d  = t % ND;
    int b  = t / ND;          // block-uniform
    int w4 = qw * 4;

    __shared__ float sflow[3 * NG3];
    {
        const float* fb = flow + b * 3 * NG3;
        for (int i = threadIdx.x; i < 3 * NG3; i += 256)
            sflow[i] = fb[i];
    }
    __syncthreads();

    // ---- coarse-flow interp, z/y reduction hoisted (d,h fixed per thread)
    const float s = 7.0f / 159.0f;
    float cz = d * s, cy = h * s;
    int izb = min((int)cz, NG - 2); float fz = cz - izb;   // exact clamp trick
    int iyb = min((int)cy, NG - 2); float fy = cy - iyb;

    float cx0 = w4 * s;
    int ixa = min((int)cx0, NG - 2);
    int ix2 = min(ixa + 2, NG - 1);

    // e[ch][j] = flow bilinear-reduced over (z,y) at x-index ixa+j (j=0,1,2)
    float e[3][3];
#pragma unroll
    for (int ch = 0; ch < 3; ++ch) {
        int base = ch * NG3 + (izb * NG + iyb) * NG;
#pragma unroll
        for (int j = 0; j < 3; ++j) {
            int ix = (j == 2) ? ix2 : (ixa + j);
            float f00 = sflow[base + ix];
            float f01 = sflow[base + NG + ix];
            float f10 = sflow[base + NG * NG + ix];
            float f11 = sflow[base + NG * NG + NG + ix];
            float a0 = f00 + (f01 - f00) * fy;
            float a1 = f10 + (f11 - f10) * fy;
            e[ch][j] = a0 + (a1 - a0) * fz;
        }
    }

    const float* xc0 = x + (size_t)(b * NC + 0) * DHW;
    const float* xc1 = x + (size_t)(b * NC + 1) * DHW;
    float r0[4], r1[4];

#pragma unroll
    for (int i = 0; i < 4; ++i) {
        int w = w4 + i;
        float cx = cx0 + (float)i * s;
        int ixb = min((int)cx, NG - 2);
        int oi  = ixb - ixa;             // 0 or 1 (4 voxels < one coarse cell)
        float fx = cx - ixb;

        float s0, s1;
        s0 = oi ? e[0][1] : e[0][0];  s1 = oi ? e[0][2] : e[0][1];
        float ux = s0 + (s1 - s0) * fx;
        s0 = oi ? e[1][1] : e[1][0];  s1 = oi ? e[1][2] : e[1][1];
        float uy = s0 + (s1 - s0) * fx;
        s0 = oi ? e[2][1] : e[2][0];  s1 = oi ? e[2][2] : e[2][1];
        float uz = s0 + (s1 - s0) * fx;

        float sx = (float)w + ux * 79.5f;
        float sy = (float)h + uy * 79.5f;
        float sz = (float)d + uz * 79.5f;
        sx = reflect_mirror(sx, (float)(NW - 1));
        sy = reflect_mirror(sy, (float)(NH - 1));
        sz = reflect_mirror(sz, (float)(ND - 1));

        // exact clamp trick: xb<=158, gx in [0,1]; kills the x1=min(x0+1,·)
        // special case AND makes the corner pair provably adjacent (dwordx2)
        int xb = min((int)sx, NW - 2); float gx = sx - xb;
        int yb = min((int)sy, NH - 2); float gy = sy - yb;
        int zb = min((int)sz, ND - 2); float gz = sz - zb;

        int off = (zb * NH + yb) * NW + xb;
        {
            const float* p = xc0 + off;
            float v00 = lerp2(p, gx);
            float v01 = lerp2(p + NW, gx);
            float v10 = lerp2(p + HWSZ, gx);
            float v11 = lerp2(p + HWSZ + NW, gx);
            float a0 = v00 + (v01 - v00) * gy;
            float a1 = v10 + (v11 - v10) * gy;
            r0[i] = a0 + (a1 - a0) * gz;
        }
        {
            const float* p = xc1 + off;
            float v00 = lerp2(p, gx);
            float v01 = lerp2(p + NW, gx);
            float v10 = lerp2(p + HWSZ, gx);
            float v11 = lerp2(p + HWSZ + NW, gx);
            float a0 = v00 + (v01 - v00) * gy;
            float a1 = v10 + (v11 - v10) * gy;
            r1[i] = a0 + (a1 - a0) * gz;
        }
    }

    size_t opos = (size_t)(d * NH + h) * NW + w4;   // 16B-aligned (w4 % 4 == 0)
    v4f o0 = { r0[0], r0[1], r0[2], r0[3] };
    v4f o1 = { r1[0], r1[1], r1[2], r1[3] };
    __builtin_nontemporal_store(o0, (v4f*)(out + (size_t)(b * NC + 0) * DHW + opos));
    __builtin_nontemporal_store(o1, (v4f*)(out + (size_t)(b * NC + 1) * DHW + opos));
}

extern "C" void kernel_launch(void* const* d_in, const int* in_sizes, int n_in,
                              void* d_out, int out_size, void* d_ws, size_t ws_size,
                              hipStream_t stream) {
    const float* x    = (const float*)d_in[0];
    const float* flow = (const float*)d_in[1];
    float* out = (float*)d_out;
    int block = 256;
    int grid = NQ / block;   // 16000, divisible by 8 for the XCD swizzle
    elastic_deform_kernel<<<grid, block, 0, stream>>>(x, flow, out);
}